// Round 1
// baseline (2794.113 us; speedup 1.0000x reference)
//
#include <hip/hip_runtime.h>
#include <math.h>

#define FEAT 128

// One edge per 32-lane group: gather x[sender] as float4 (32 lanes * 16B = 512B row),
// scale by per-edge weight (computed inline, all uniform inputs), scatter-atomic into agg.
__global__ __launch_bounds__(256) void scatter_kernel(
    const float4* __restrict__ x4,
    const int* __restrict__ sender,
    const int* __restrict__ receiver,
    const float* __restrict__ edge_len,
    const float* __restrict__ log_scale,
    const float* __restrict__ filter_w,
    const float* __restrict__ filter_b,
    float* __restrict__ agg,
    float* __restrict__ deg,
    int E)
{
    int gid = blockIdx.x * 256 + threadIdx.x;
    int e = gid >> 5;          // 32 threads per edge
    if (e >= E) return;
    int lane = gid & 31;

    int s = sender[e];
    int r = receiver[e];
    float d = edge_len[e];

    // weight = exp(-(max(d/(scale+1e-6),0))^2) * sigmoid(d*fw + fb), nan_to_num
    float scale = expf(log_scale[0]) + 1e-6f;
    float t = fmaxf(d / scale, 0.0f);
    float decay = expf(-t * t);
    float g = 1.0f / (1.0f + expf(-(d * filter_w[0] + filter_b[0])));
    float w = decay * g;
    if (!isfinite(w)) w = 0.0f;

    float4 xv = x4[s * (FEAT / 4) + lane];
    float* dst = agg + r * FEAT + lane * 4;
    unsafeAtomicAdd(dst + 0, w * xv.x);
    unsafeAtomicAdd(dst + 1, w * xv.y);
    unsafeAtomicAdd(dst + 2, w * xv.z);
    unsafeAtomicAdd(dst + 3, w * xv.w);
    if (lane == 0) unsafeAtomicAdd(&deg[r], 1.0f);
}

// out[n,j] = x[n,j] + (1/max(deg[n],1)) * sum_k agg[n,k] * W[k,j]
// W (64KB) staged in LDS; 2 nodes per 256-thread block iteration (thread = column).
// Note: (agg/deg) @ W == (agg @ W) / deg  -> divide once at the end.
__global__ __launch_bounds__(256) void finalize_kernel(
    const float* __restrict__ x,
    const float* __restrict__ agg,
    const float* __restrict__ deg,
    const float* __restrict__ Wm,
    float* __restrict__ out,
    int N)
{
    __shared__ float Ws[FEAT * FEAT];   // 64 KB -> 2 blocks/CU
    for (int i = threadIdx.x * 4; i < FEAT * FEAT; i += 256 * 4) {
        *(float4*)&Ws[i] = *(const float4*)&Wm[i];
    }
    __syncthreads();

    int half = threadIdx.x >> 7;          // 0 or 1: which node of the pair
    int j = threadIdx.x & (FEAT - 1);     // output column

    for (int n0 = blockIdx.x * 2; n0 < N; n0 += gridDim.x * 2) {
        int n = n0 + half;
        if (n < N) {
            const float* arow = agg + (size_t)n * FEAT;
            float acc = 0.0f;
            #pragma unroll 16
            for (int k = 0; k < FEAT; ++k) {
                acc = fmaf(arow[k], Ws[k * FEAT + j], acc);
            }
            float invd = 1.0f / fmaxf(deg[n], 1.0f);
            size_t idx = (size_t)n * FEAT + j;
            out[idx] = x[idx] + invd * acc;
        }
    }
}

extern "C" void kernel_launch(void* const* d_in, const int* in_sizes, int n_in,
                              void* d_out, int out_size, void* d_ws, size_t ws_size,
                              hipStream_t stream) {
    const float* x         = (const float*)d_in[0];
    const int*   ei        = (const int*)d_in[1];   // [2, E] flat: sender then receiver
    const float* edge_len  = (const float*)d_in[2];
    const float* W_mix     = (const float*)d_in[3];
    const float* log_scale = (const float*)d_in[4];
    const float* filter_w  = (const float*)d_in[5];
    const float* filter_b  = (const float*)d_in[6];
    float* out = (float*)d_out;

    const int N = in_sizes[0] / FEAT;     // 50000
    const int E = in_sizes[1] / 2;        // 1500000
    const int* sender   = ei;
    const int* receiver = ei + E;

    // workspace: agg [N*FEAT] f32, then deg [N] f32 (contiguous so one memset)
    float* agg = (float*)d_ws;
    float* deg = agg + (size_t)N * FEAT;

    hipMemsetAsync(agg, 0, ((size_t)N * FEAT + N) * sizeof(float), stream);

    int scatter_blocks = (E * 32 + 255) / 256;   // one 32-lane group per edge
    scatter_kernel<<<scatter_blocks, 256, 0, stream>>>(
        (const float4*)x, sender, receiver, edge_len,
        log_scale, filter_w, filter_b, agg, deg, E);

    finalize_kernel<<<512, 256, 0, stream>>>(x, agg, deg, W_mix, out, N);
}

// Round 2
// 613.303 us; speedup vs baseline: 4.5558x; 4.5558x over previous
//
#include <hip/hip_runtime.h>
#include <math.h>

#define FEAT 128

__device__ __forceinline__ float edge_weight(float d, float scale, float fw, float fb) {
    // scale already includes +1e-6
    float t = fmaxf(d / scale, 0.0f);
    float decay = expf(-t * t);
    float g = 1.0f / (1.0f + expf(-(d * fw + fb)));
    float w = decay * g;
    if (!isfinite(w)) w = 0.0f;
    return w;
}

// ---------------- CSR build ----------------

__global__ __launch_bounds__(256) void hist_kernel(const int* __restrict__ recv,
                                                   int* __restrict__ off, int E) {
    int e = blockIdx.x * 256 + threadIdx.x;
    if (e < E) atomicAdd(&off[recv[e] + 1], 1);
}

// Single-block scan over N counts stored at off[1..N]; writes inclusive sums back
// into off[1..N] (so off[] becomes CSR offsets) and segment starts into cursor[].
__global__ __launch_bounds__(1024) void scan_kernel(int* __restrict__ off,
                                                    int* __restrict__ cursor, int N) {
    __shared__ int part[1024];
    int t = threadIdx.x;
    int chunk = (N + 1023) >> 10;
    int lo = t * chunk, hi = min(lo + chunk, N);
    int s = 0;
    for (int i = lo; i < hi; ++i) s += off[1 + i];
    part[t] = s;
    __syncthreads();
    for (int d = 1; d < 1024; d <<= 1) {
        int v = (t >= d) ? part[t - d] : 0;
        __syncthreads();
        part[t] += v;
        __syncthreads();
    }
    int run = part[t] - s;  // exclusive prefix of this thread's chunk
    for (int i = lo; i < hi; ++i) {
        int c = off[1 + i];
        cursor[i] = run;        // segment start for node i
        run += c;
        off[1 + i] = run;       // inclusive -> CSR offset for node i+1
    }
    if (t == 0) off[0] = 0;
}

// Reorder edges by receiver: one packed (weight<<32 | sender) 8B record per edge.
__global__ __launch_bounds__(256) void sort_kernel(
    const int* __restrict__ sender, const int* __restrict__ recv,
    const float* __restrict__ edge_len,
    const float* __restrict__ log_scale, const float* __restrict__ filter_w,
    const float* __restrict__ filter_b,
    int* __restrict__ cursor, unsigned long long* __restrict__ sorted_sw, int E) {
    int e = blockIdx.x * 256 + threadIdx.x;
    if (e >= E) return;
    float scale = expf(log_scale[0]) + 1e-6f;
    float w = edge_weight(edge_len[e], scale, filter_w[0], filter_b[0]);
    int pos = atomicAdd(&cursor[recv[e]], 1);
    unsigned long long sw =
        ((unsigned long long)__float_as_uint(w) << 32) | (unsigned int)sender[e];
    sorted_sw[pos] = sw;
}

// ---------------- aggregation (no atomics) ----------------
// 32 lanes per node; lane holds float4 of the feature row. One store per node.
__global__ __launch_bounds__(256) void aggregate_kernel(
    const float4* __restrict__ x4, const unsigned long long* __restrict__ sw,
    const int* __restrict__ off, float4* __restrict__ agg4, int N) {
    int gid = blockIdx.x * 256 + threadIdx.x;
    int n = gid >> 5;
    if (n >= N) return;
    int lane = gid & 31;
    int lo = off[n], hi = off[n + 1];
    float4 acc = make_float4(0.f, 0.f, 0.f, 0.f);
    int i = lo;
    for (; i + 2 <= hi; i += 2) {
        unsigned long long a = sw[i];
        unsigned long long b = sw[i + 1];
        int s0 = (int)(unsigned int)a;
        float w0 = __uint_as_float((unsigned int)(a >> 32));
        int s1 = (int)(unsigned int)b;
        float w1 = __uint_as_float((unsigned int)(b >> 32));
        float4 v0 = x4[(size_t)s0 * (FEAT / 4) + lane];
        float4 v1 = x4[(size_t)s1 * (FEAT / 4) + lane];
        acc.x = fmaf(w0, v0.x, acc.x);
        acc.y = fmaf(w0, v0.y, acc.y);
        acc.z = fmaf(w0, v0.z, acc.z);
        acc.w = fmaf(w0, v0.w, acc.w);
        acc.x = fmaf(w1, v1.x, acc.x);
        acc.y = fmaf(w1, v1.y, acc.y);
        acc.z = fmaf(w1, v1.z, acc.z);
        acc.w = fmaf(w1, v1.w, acc.w);
    }
    if (i < hi) {
        unsigned long long a = sw[i];
        int s0 = (int)(unsigned int)a;
        float w0 = __uint_as_float((unsigned int)(a >> 32));
        float4 v0 = x4[(size_t)s0 * (FEAT / 4) + lane];
        acc.x = fmaf(w0, v0.x, acc.x);
        acc.y = fmaf(w0, v0.y, acc.y);
        acc.z = fmaf(w0, v0.z, acc.z);
        acc.w = fmaf(w0, v0.w, acc.w);
    }
    agg4[(size_t)n * (FEAT / 4) + lane] = acc;
}

// ---------------- epilogue: out = x + (agg/deg) @ W ----------------
__global__ __launch_bounds__(256) void finalize_kernel(
    const float* __restrict__ x, const float* __restrict__ agg,
    const int* __restrict__ off, const float* __restrict__ Wm,
    float* __restrict__ out, int N) {
    __shared__ float Ws[FEAT * FEAT];  // 64 KB
    for (int i = threadIdx.x * 4; i < FEAT * FEAT; i += 256 * 4) {
        *(float4*)&Ws[i] = *(const float4*)&Wm[i];
    }
    __syncthreads();

    int half = threadIdx.x >> 7;
    int j = threadIdx.x & (FEAT - 1);

    for (int n0 = blockIdx.x * 2; n0 < N; n0 += gridDim.x * 2) {
        int n = n0 + half;
        if (n < N) {
            const float* arow = agg + (size_t)n * FEAT;
            float acc = 0.0f;
            #pragma unroll 16
            for (int k = 0; k < FEAT; ++k) {
                acc = fmaf(arow[k], Ws[k * FEAT + j], acc);
            }
            float degf = (float)(off[n + 1] - off[n]);
            float invd = 1.0f / fmaxf(degf, 1.0f);
            size_t idx = (size_t)n * FEAT + j;
            out[idx] = x[idx] + invd * acc;
        }
    }
}

// ---------------- fallback (R1 atomic path, if ws too small) ----------------
__global__ __launch_bounds__(256) void scatter_fallback(
    const float4* __restrict__ x4, const int* __restrict__ sender,
    const int* __restrict__ receiver, const float* __restrict__ edge_len,
    const float* __restrict__ log_scale, const float* __restrict__ filter_w,
    const float* __restrict__ filter_b, float* __restrict__ agg,
    float* __restrict__ deg, int E) {
    int gid = blockIdx.x * 256 + threadIdx.x;
    int e = gid >> 5;
    if (e >= E) return;
    int lane = gid & 31;
    int s = sender[e];
    int r = receiver[e];
    float scale = expf(log_scale[0]) + 1e-6f;
    float w = edge_weight(edge_len[e], scale, filter_w[0], filter_b[0]);
    float4 xv = x4[s * (FEAT / 4) + lane];
    float* dst = agg + (size_t)r * FEAT + lane * 4;
    unsafeAtomicAdd(dst + 0, w * xv.x);
    unsafeAtomicAdd(dst + 1, w * xv.y);
    unsafeAtomicAdd(dst + 2, w * xv.z);
    unsafeAtomicAdd(dst + 3, w * xv.w);
    if (lane == 0) unsafeAtomicAdd(&deg[r], 1.0f);
}

__global__ __launch_bounds__(256) void finalize_fallback(
    const float* __restrict__ x, const float* __restrict__ agg,
    const float* __restrict__ deg, const float* __restrict__ Wm,
    float* __restrict__ out, int N) {
    __shared__ float Ws[FEAT * FEAT];
    for (int i = threadIdx.x * 4; i < FEAT * FEAT; i += 256 * 4)
        *(float4*)&Ws[i] = *(const float4*)&Wm[i];
    __syncthreads();
    int half = threadIdx.x >> 7;
    int j = threadIdx.x & (FEAT - 1);
    for (int n0 = blockIdx.x * 2; n0 < N; n0 += gridDim.x * 2) {
        int n = n0 + half;
        if (n < N) {
            const float* arow = agg + (size_t)n * FEAT;
            float acc = 0.0f;
            #pragma unroll 16
            for (int k = 0; k < FEAT; ++k) acc = fmaf(arow[k], Ws[k * FEAT + j], acc);
            float invd = 1.0f / fmaxf(deg[n], 1.0f);
            size_t idx = (size_t)n * FEAT + j;
            out[idx] = x[idx] + invd * acc;
        }
    }
}

extern "C" void kernel_launch(void* const* d_in, const int* in_sizes, int n_in,
                              void* d_out, int out_size, void* d_ws, size_t ws_size,
                              hipStream_t stream) {
    const float* x         = (const float*)d_in[0];
    const int*   ei        = (const int*)d_in[1];
    const float* edge_len  = (const float*)d_in[2];
    const float* W_mix     = (const float*)d_in[3];
    const float* log_scale = (const float*)d_in[4];
    const float* filter_w  = (const float*)d_in[5];
    const float* filter_b  = (const float*)d_in[6];
    float* out = (float*)d_out;

    const int N = in_sizes[0] / FEAT;
    const int E = in_sizes[1] / 2;
    const int* sender   = ei;
    const int* receiver = ei + E;

    // workspace layout (CSR path)
    size_t sorted_bytes = (size_t)E * 8;
    size_t off_bytes    = (((size_t)(N + 1) * 4) + 63) & ~(size_t)63;
    size_t cur_bytes    = (((size_t)N * 4) + 63) & ~(size_t)63;
    size_t agg_bytes    = (size_t)N * FEAT * 4;
    size_t needed = sorted_bytes + off_bytes + cur_bytes + agg_bytes;

    if (ws_size >= needed) {
        char* p = (char*)d_ws;
        unsigned long long* sorted_sw = (unsigned long long*)p;  p += sorted_bytes;
        int*   off    = (int*)p;                                 p += off_bytes;
        int*   cursor = (int*)p;                                 p += cur_bytes;
        float* agg    = (float*)p;

        // zero the count array only (agg/sorted/cursor are fully overwritten)
        hipMemsetAsync(off, 0, (size_t)(N + 1) * 4, stream);

        int eblocks = (E + 255) / 256;
        hist_kernel<<<eblocks, 256, 0, stream>>>(receiver, off, E);
        scan_kernel<<<1, 1024, 0, stream>>>(off, cursor, N);
        sort_kernel<<<eblocks, 256, 0, stream>>>(sender, receiver, edge_len,
                                                 log_scale, filter_w, filter_b,
                                                 cursor, sorted_sw, E);
        int ablocks = (N * 32 + 255) / 256;
        aggregate_kernel<<<ablocks, 256, 0, stream>>>((const float4*)x, sorted_sw,
                                                      off, (float4*)agg, N);
        finalize_kernel<<<512, 256, 0, stream>>>(x, agg, off, W_mix, out, N);
    } else {
        float* agg = (float*)d_ws;
        float* deg = agg + (size_t)N * FEAT;
        hipMemsetAsync(agg, 0, ((size_t)N * FEAT + N) * sizeof(float), stream);
        int sblocks = (E * 32 + 255) / 256;
        scatter_fallback<<<sblocks, 256, 0, stream>>>(
            (const float4*)x, sender, receiver, edge_len,
            log_scale, filter_w, filter_b, agg, deg, E);
        finalize_fallback<<<512, 256, 0, stream>>>(x, agg, deg, W_mix, out, N);
    }
}

// Round 4
// 478.085 us; speedup vs baseline: 5.8444x; 1.2828x over previous
//
#include <hip/hip_runtime.h>
#include <math.h>

#define FEAT 128

__device__ __forceinline__ float edge_weight(float d, float scale, float fw, float fb) {
    // scale already includes +1e-6
    float t = fmaxf(d / scale, 0.0f);
    float decay = expf(-t * t);
    float g = 1.0f / (1.0f + expf(-(d * fw + fb)));
    float w = decay * g;
    if (!isfinite(w)) w = 0.0f;
    return w;
}

// ---------------- bf16 helpers ----------------
__device__ __forceinline__ unsigned int bf16_rne(float f) {
    unsigned int b = __float_as_uint(f);
    return (b + 0x7FFFu + ((b >> 16) & 1u)) >> 16;
}

// ---------------- x -> bf16 table ----------------
__global__ __launch_bounds__(256) void convert_kernel(const float4* __restrict__ x4,
                                                      uint2* __restrict__ xbf,
                                                      int n4) {
    int i = blockIdx.x * 256 + threadIdx.x;
    if (i >= n4) return;
    float4 v = x4[i];
    uint2 o;
    o.x = (bf16_rne(v.y) << 16) | bf16_rne(v.x);
    o.y = (bf16_rne(v.w) << 16) | bf16_rne(v.z);
    xbf[i] = o;
}

// ---------------- CSR build ----------------
__global__ __launch_bounds__(256) void hist_kernel(const int* __restrict__ recv,
                                                   int* __restrict__ off, int E) {
    int e = blockIdx.x * 256 + threadIdx.x;
    if (e < E) atomicAdd(&off[recv[e] + 1], 1);
}

__global__ __launch_bounds__(1024) void scan_kernel(int* __restrict__ off,
                                                    int* __restrict__ cursor, int N) {
    __shared__ int part[1024];
    int t = threadIdx.x;
    int chunk = (N + 1023) >> 10;
    int lo = t * chunk, hi = min(lo + chunk, N);
    int s = 0;
    for (int i = lo; i < hi; ++i) s += off[1 + i];
    part[t] = s;
    __syncthreads();
    for (int d = 1; d < 1024; d <<= 1) {
        int v = (t >= d) ? part[t - d] : 0;
        __syncthreads();
        part[t] += v;
        __syncthreads();
    }
    int run = part[t] - s;
    for (int i = lo; i < hi; ++i) {
        int c = off[1 + i];
        cursor[i] = run;
        run += c;
        off[1 + i] = run;
    }
    if (t == 0) off[0] = 0;
}

__global__ __launch_bounds__(256) void sort_kernel(
    const int* __restrict__ sender, const int* __restrict__ recv,
    const float* __restrict__ edge_len,
    const float* __restrict__ log_scale, const float* __restrict__ filter_w,
    const float* __restrict__ filter_b,
    int* __restrict__ cursor, unsigned long long* __restrict__ sorted_sw, int E) {
    int e = blockIdx.x * 256 + threadIdx.x;
    if (e >= E) return;
    float scale = expf(log_scale[0]) + 1e-6f;
    float w = edge_weight(edge_len[e], scale, filter_w[0], filter_b[0]);
    int pos = atomicAdd(&cursor[recv[e]], 1);
    unsigned long long sw =
        ((unsigned long long)__float_as_uint(w) << 32) | (unsigned int)sender[e];
    sorted_sw[pos] = sw;
}

// ---------------- aggregation: 16 lanes/node, bf16 gather, f32 accumulate ----
// Output agg stored bf16-packed (uint4 = 8 features per lane) in d_ws.
__device__ __forceinline__ void accum8(float acc[8], uint4 u, float w) {
    acc[0] = fmaf(w, __uint_as_float(u.x << 16), acc[0]);
    acc[1] = fmaf(w, __uint_as_float(u.x & 0xFFFF0000u), acc[1]);
    acc[2] = fmaf(w, __uint_as_float(u.y << 16), acc[2]);
    acc[3] = fmaf(w, __uint_as_float(u.y & 0xFFFF0000u), acc[3]);
    acc[4] = fmaf(w, __uint_as_float(u.z << 16), acc[4]);
    acc[5] = fmaf(w, __uint_as_float(u.z & 0xFFFF0000u), acc[5]);
    acc[6] = fmaf(w, __uint_as_float(u.w << 16), acc[6]);
    acc[7] = fmaf(w, __uint_as_float(u.w & 0xFFFF0000u), acc[7]);
}

__global__ __launch_bounds__(256) void aggregate_kernel(
    const uint4* __restrict__ xbf4, const unsigned long long* __restrict__ sw,
    const int* __restrict__ off, uint4* __restrict__ agg_bf4, int N) {
    int gid = blockIdx.x * 256 + threadIdx.x;
    int n = gid >> 4;
    if (n >= N) return;
    int lane = gid & 15;
    int lo = off[n], hi = off[n + 1];
    float acc[8] = {0.f, 0.f, 0.f, 0.f, 0.f, 0.f, 0.f, 0.f};
    int i = lo;
    for (; i + 2 <= hi; i += 2) {
        unsigned long long a = sw[i];
        unsigned long long b = sw[i + 1];
        int s0 = (int)(unsigned int)a;
        float w0 = __uint_as_float((unsigned int)(a >> 32));
        int s1 = (int)(unsigned int)b;
        float w1 = __uint_as_float((unsigned int)(b >> 32));
        uint4 u0 = xbf4[(size_t)s0 * 16 + lane];
        uint4 u1 = xbf4[(size_t)s1 * 16 + lane];
        accum8(acc, u0, w0);
        accum8(acc, u1, w1);
    }
    if (i < hi) {
        unsigned long long a = sw[i];
        int s0 = (int)(unsigned int)a;
        float w0 = __uint_as_float((unsigned int)(a >> 32));
        uint4 u0 = xbf4[(size_t)s0 * 16 + lane];
        accum8(acc, u0, w0);
    }
    uint4 o;
    o.x = (bf16_rne(acc[1]) << 16) | bf16_rne(acc[0]);
    o.y = (bf16_rne(acc[3]) << 16) | bf16_rne(acc[2]);
    o.z = (bf16_rne(acc[5]) << 16) | bf16_rne(acc[4]);
    o.w = (bf16_rne(acc[7]) << 16) | bf16_rne(acc[6]);
    agg_bf4[(size_t)n * 16 + lane] = o;
}

// ---------------- finalize: tiled GEMM, out = x + (agg/deg) @ W --------------
// Block = 64 nodes x 128 cols (two 64-col halves). agg read from ws (bf16),
// expanded to f32 in LDS with xor swizzle. Thread computes a 4x4 register tile.
// d_out is write-only and written by this kernel alone.
__global__ __launch_bounds__(256) void finalize_kernel(
    const float* __restrict__ x, const uint4* __restrict__ agg_bf4,
    const int* __restrict__ off, const float* __restrict__ Wm,
    float* __restrict__ out, int N) {
    __shared__ float aggS[64 * 128];  // 32 KB
    __shared__ float Ws[128 * 64];    // 32 KB
    const int n0 = blockIdx.x * 64;

    // stage agg tile: bf16 -> f32, swizzled float4 chunks
    for (int i = threadIdx.x; i < 64 * 16; i += 256) {
        int r = i >> 4;       // row in tile
        int q = i & 15;       // uint4 (8 features) within row
        int n = n0 + r;
        uint4 u = make_uint4(0u, 0u, 0u, 0u);
        if (n < N) u = agg_bf4[(size_t)n * 16 + q];
        float4 f0, f1;
        f0.x = __uint_as_float(u.x << 16);
        f0.y = __uint_as_float(u.x & 0xFFFF0000u);
        f0.z = __uint_as_float(u.y << 16);
        f0.w = __uint_as_float(u.y & 0xFFFF0000u);
        f1.x = __uint_as_float(u.z << 16);
        f1.y = __uint_as_float(u.z & 0xFFFF0000u);
        f1.z = __uint_as_float(u.w << 16);
        f1.w = __uint_as_float(u.w & 0xFFFF0000u);
        int m = (r >> 2) & 7;
        ((float4*)aggS)[r * 32 + ((2 * q) ^ m)] = f0;
        ((float4*)aggS)[r * 32 + ((2 * q + 1) ^ m)] = f1;
    }

    const int tc = threadIdx.x & 15;  // 16 col-groups * 4 cols = 64 cols
    const int tr = threadIdx.x >> 4;  // 16 row-groups * 4 nodes = 64 nodes

    float invd[4];
#pragma unroll
    for (int i = 0; i < 4; ++i) {
        int n = n0 + 4 * tr + i;
        float degf = 1.0f;
        if (n < N) degf = fmaxf((float)(off[n + 1] - off[n]), 1.0f);
        invd[i] = 1.0f / degf;
    }

    for (int h = 0; h < 2; ++h) {
        // stage W[:, 64h : 64h+64]
        for (int i = threadIdx.x; i < 128 * 16; i += 256) {
            int k = i >> 4;
            int j4 = i & 15;
            ((float4*)Ws)[k * 16 + j4] = ((const float4*)Wm)[k * 32 + h * 16 + j4];
        }
        __syncthreads();  // covers aggS (h=0) and Ws

        float acc[4][4];
#pragma unroll
        for (int i = 0; i < 4; ++i)
#pragma unroll
            for (int c = 0; c < 4; ++c) acc[i][c] = 0.f;

#pragma unroll 4
        for (int k0 = 0; k0 < 128; k0 += 4) {
            float4 ar4[4];
            const int chunk = (k0 >> 2) ^ (tr & 7);
#pragma unroll
            for (int i = 0; i < 4; ++i) {
                int r = 4 * tr + i;
                ar4[i] = ((const float4*)aggS)[r * 32 + chunk];
            }
            float4 wv4[4];
#pragma unroll
            for (int kk = 0; kk < 4; ++kk)
                wv4[kk] = *(const float4*)&Ws[(k0 + kk) * 64 + tc * 4];

            float wvv[4][4];
#pragma unroll
            for (int kk = 0; kk < 4; ++kk) {
                wvv[kk][0] = wv4[kk].x; wvv[kk][1] = wv4[kk].y;
                wvv[kk][2] = wv4[kk].z; wvv[kk][3] = wv4[kk].w;
            }
#pragma unroll
            for (int i = 0; i < 4; ++i) {
                float av[4] = {ar4[i].x, ar4[i].y, ar4[i].z, ar4[i].w};
#pragma unroll
                for (int kk = 0; kk < 4; ++kk)
#pragma unroll
                    for (int c = 0; c < 4; ++c)
                        acc[i][c] = fmaf(av[kk], wvv[kk][c], acc[i][c]);
            }
        }

        // epilogue for this col-half
#pragma unroll
        for (int i = 0; i < 4; ++i) {
            int n = n0 + 4 * tr + i;
            if (n < N) {
                size_t base = (size_t)n * FEAT + h * 64 + tc * 4;
                float4 xv = *(const float4*)&x[base];
                float4 o;
                o.x = xv.x + invd[i] * acc[i][0];
                o.y = xv.y + invd[i] * acc[i][1];
                o.z = xv.z + invd[i] * acc[i][2];
                o.w = xv.w + invd[i] * acc[i][3];
                *(float4*)&out[base] = o;
            }
        }
        __syncthreads();  // before next half overwrites Ws
    }
}

// ---------------- fallback (atomic path, only if ws too small) ---------------
__global__ __launch_bounds__(256) void scatter_fallback(
    const float4* __restrict__ x4, const int* __restrict__ sender,
    const int* __restrict__ receiver, const float* __restrict__ edge_len,
    const float* __restrict__ log_scale, const float* __restrict__ filter_w,
    const float* __restrict__ filter_b, float* __restrict__ agg,
    float* __restrict__ deg, int E) {
    int gid = blockIdx.x * 256 + threadIdx.x;
    int e = gid >> 5;
    if (e >= E) return;
    int lane = gid & 31;
    int s = sender[e];
    int r = receiver[e];
    float scale = expf(log_scale[0]) + 1e-6f;
    float w = edge_weight(edge_len[e], scale, filter_w[0], filter_b[0]);
    float4 xv = x4[s * (FEAT / 4) + lane];
    float* dst = agg + (size_t)r * FEAT + lane * 4;
    unsafeAtomicAdd(dst + 0, w * xv.x);
    unsafeAtomicAdd(dst + 1, w * xv.y);
    unsafeAtomicAdd(dst + 2, w * xv.z);
    unsafeAtomicAdd(dst + 3, w * xv.w);
    if (lane == 0) unsafeAtomicAdd(&deg[r], 1.0f);
}

__global__ __launch_bounds__(256) void finalize_fallback(
    const float* __restrict__ x, const float* __restrict__ agg,
    const float* __restrict__ deg, const float* __restrict__ Wm,
    float* __restrict__ out, int N) {
    __shared__ float Wsf[FEAT * FEAT];
    for (int i = threadIdx.x * 4; i < FEAT * FEAT; i += 256 * 4)
        *(float4*)&Wsf[i] = *(const float4*)&Wm[i];
    __syncthreads();
    int half = threadIdx.x >> 7;
    int j = threadIdx.x & (FEAT - 1);
    for (int n0 = blockIdx.x * 2; n0 < N; n0 += gridDim.x * 2) {
        int n = n0 + half;
        if (n < N) {
            const float* arow = agg + (size_t)n * FEAT;
            float acc = 0.0f;
#pragma unroll 16
            for (int k = 0; k < FEAT; ++k) acc = fmaf(arow[k], Wsf[k * FEAT + j], acc);
            float invd = 1.0f / fmaxf(deg[n], 1.0f);
            size_t idx = (size_t)n * FEAT + j;
            out[idx] = x[idx] + invd * acc;
        }
    }
}

extern "C" void kernel_launch(void* const* d_in, const int* in_sizes, int n_in,
                              void* d_out, int out_size, void* d_ws, size_t ws_size,
                              hipStream_t stream) {
    const float* x         = (const float*)d_in[0];
    const int*   ei        = (const int*)d_in[1];
    const float* edge_len  = (const float*)d_in[2];
    const float* W_mix     = (const float*)d_in[3];
    const float* log_scale = (const float*)d_in[4];
    const float* filter_w  = (const float*)d_in[5];
    const float* filter_b  = (const float*)d_in[6];
    float* out = (float*)d_out;

    const int N = in_sizes[0] / FEAT;
    const int E = in_sizes[1] / 2;
    const int* sender   = ei;
    const int* receiver = ei + E;

    // ws layout (CSR path): xbf [N*128 bf16], agg_bf [N*128 bf16],
    // sorted_sw [E*8], off [(N+1)*4], cursor [N*4]   -> ~38.0 MB total
    size_t xbf_bytes    = (size_t)N * FEAT * 2;
    size_t aggb_bytes   = (size_t)N * FEAT * 2;
    size_t sorted_bytes = (size_t)E * 8;
    size_t off_bytes    = (((size_t)(N + 1) * 4) + 63) & ~(size_t)63;
    size_t cur_bytes    = (((size_t)N * 4) + 63) & ~(size_t)63;
    size_t needed = xbf_bytes + aggb_bytes + sorted_bytes + off_bytes + cur_bytes;

    if (ws_size >= needed) {
        char* p = (char*)d_ws;
        uint2* xbf    = (uint2*)p;                              p += xbf_bytes;
        uint4* agg_bf = (uint4*)p;                              p += aggb_bytes;
        unsigned long long* sorted_sw = (unsigned long long*)p; p += sorted_bytes;
        int* off    = (int*)p;                                  p += off_bytes;
        int* cursor = (int*)p;

        hipMemsetAsync(off, 0, (size_t)(N + 1) * 4, stream);

        int cblocks = (N * (FEAT / 4) + 255) / 256;
        convert_kernel<<<cblocks, 256, 0, stream>>>((const float4*)x, xbf,
                                                    N * (FEAT / 4));
        int eblocks = (E + 255) / 256;
        hist_kernel<<<eblocks, 256, 0, stream>>>(receiver, off, E);
        scan_kernel<<<1, 1024, 0, stream>>>(off, cursor, N);
        sort_kernel<<<eblocks, 256, 0, stream>>>(sender, receiver, edge_len,
                                                 log_scale, filter_w, filter_b,
                                                 cursor, sorted_sw, E);
        int ablocks = (N * 16 + 255) / 256;
        aggregate_kernel<<<ablocks, 256, 0, stream>>>((const uint4*)xbf, sorted_sw,
                                                      off, agg_bf, N);
        int fblocks = (N + 63) / 64;
        finalize_kernel<<<fblocks, 256, 0, stream>>>(x, (const uint4*)agg_bf, off,
                                                     W_mix, out, N);
    } else {
        float* agg = (float*)d_ws;
        float* deg = agg + (size_t)N * FEAT;
        hipMemsetAsync(agg, 0, ((size_t)N * FEAT + N) * sizeof(float), stream);
        int sblocks = (E * 32 + 255) / 256;
        scatter_fallback<<<sblocks, 256, 0, stream>>>(
            (const float4*)x, sender, receiver, edge_len,
            log_scale, filter_w, filter_b, agg, deg, E);
        finalize_fallback<<<512, 256, 0, stream>>>(x, agg, deg, W_mix, out, N);
    }
}